// Round 7
// baseline (356.516 us; speedup 1.0000x reference)
//
#include <hip/hip_runtime.h>
#include <float.h>

#define DIM      512
#define NCLS     21
#define MARGIN_V 5.0f
#define NWAVES   8                 // waves per block; wave w owns d-slice [w*64, w*64+64)
#define DSLICE   (DIM / NWAVES)    // 64 floats = 16 float4
#define RPL      4                 // rows per lane: center reads amortized over 4 rows
#define ROWS_PB  (64 * RPL)        // 256 rows per block; grid 256 = exactly 1 block/CU
#define NCHUNK   8                 // 8-float chunks (2 f4) per slice; 64B line = 2 chunks
#define CLDSF    (NCLS * DIM)      // 10752 floats: centers table (43008 B)
#define SST      85                // odd scalar combine stride -> conflict-free b32
#define LDSF     (4 * 64 * SST)    // 21760 floats = 87040 B (>= centers 10752, unioned)

// Kernel 1: halfc2[c] = 0.5 * ||centers[c]||^2  -> d_ws
__global__ __launch_bounds__(64)
void center_norm_kernel(const float* __restrict__ centers,
                        float* __restrict__ halfc2) {
    const int c = blockIdx.x;
    const int t = threadIdx.x;
    float s = 0.f;
#pragma unroll
    for (int i = 0; i < DIM / 64; ++i) {
        float v = centers[c * DIM + i * 64 + t];
        s = fmaf(v, v, s);
    }
#pragma unroll
    for (int off = 32; off > 0; off >>= 1)
        s += __shfl_down(s, off, 64);
    if (t == 0) halfc2[c] = 0.5f * s;
}

// Kernel 2: 8 waves/block; wave w owns d-slice [w*64,w*64+64) of 256 rows,
// lane t owns rows {t,t+64,t+128,t+192} (acc[4][21] = 84 VGPRs). Features go
// global->VGPR in 16B-per-row q-steps (fv[4] = 16 regs live; a 64B line spans
// 2 consecutive chunks -> L2 reuse window 2 MB/XCD < 4 MB, no HBM re-fetch --
// r4's 4x over-fetch window was exactly 4 MB/XCD). Centers broadcast from LDS
// as uniform ds_read_b128, each read feeding 16 FMAs/lane: per-CU DS cost
// 8 waves x 336 x 12cyc = 13.4us, vs 67us at RPL=1 (the r2/r6 wall). Total
// liveness ~118 <= the empirical 128-VGPR cap for 512-thread blocks (r3/r5
// spilled asking for more). Chunk loop stays rolled: straight-lining 5376
// FMAs overflows the 32KB I$.
__global__ __launch_bounds__(512, 1)
void tcl_main_kernel(const float* __restrict__ feat,
                     const float* __restrict__ centers,
                     const int* __restrict__ labels,
                     const float* __restrict__ halfc2,
                     float* __restrict__ out) {
    __shared__ float lds[LDSF];

    const int tid  = threadIdx.x;
    const int w    = __builtin_amdgcn_readfirstlane(tid >> 6);  // uniform wave id
    const int t    = tid & 63;
    const int row0 = blockIdx.x * ROWS_PB;

    int labv[RPL];
    if (w == 0) {
#pragma unroll
        for (int r = 0; r < RPL; ++r) labv[r] = labels[row0 + t + r * 64];
    }

    float acc[RPL][NCLS];
#pragma unroll
    for (int r = 0; r < RPL; ++r)
#pragma unroll
        for (int c = 0; c < NCLS; ++c) acc[r][c] = 0.f;

    const float4* f4p = reinterpret_cast<const float4*>(feat);
    size_t rb[RPL];
#pragma unroll
    for (int r = 0; r < RPL; ++r)
        rb[r] = (size_t)(row0 + t + r * 64) * (DIM / 4) + (size_t)w * (DSLICE / 4);

    // stage centers table into LDS (block-cooperative, float4)
    float4* l4 = reinterpret_cast<float4*>(lds);
    {
        const float4* c4 = reinterpret_cast<const float4*>(centers);
#pragma unroll
        for (int i = 0; i < (CLDSF / 4 + 511) / 512; ++i) {
            int idx = i * 512 + tid;
            if (idx < CLDSF / 4) l4[idx] = c4[idx];
        }
    }
    __syncthreads();

    // uniform LDS base for this wave's d-slice (per-class offsets are imm)
    const float4* cl = l4 + w * (DSLICE / 4);

#pragma unroll 1
    for (int k = 0; k < NCHUNK; ++k) {
#pragma unroll
        for (int q = 0; q < 2; ++q) {
            const int fq = k * 2 + q;          // f4 index within slice, 0..15
            // 4 x global_load_dwordx4: lane reads 16B of each of its 4 rows
            float4 fv[RPL];
#pragma unroll
            for (int r = 0; r < RPL; ++r)
                fv[r] = f4p[rb[r] + fq];
            // 21 classes: one uniform b128 broadcast feeds 4 rows x 4 FMAs
#pragma unroll
            for (int c = 0; c < NCLS; ++c) {
                float4 cv = cl[c * (DIM / 4) + fq];
#pragma unroll
                for (int r = 0; r < RPL; ++r) {
                    acc[r][c] = fmaf(fv[r].x, cv.x,
                                 fmaf(fv[r].y, cv.y,
                                  fmaf(fv[r].z, cv.z,
                                   fmaf(fv[r].w, cv.w, acc[r][c]))));
                }
            }
        }
    }

    // ---- cross-wave combine: 8 -> 4 -> 2 -> 1, scalar b32, odd stride 85 ----
    float* scratch = lds;   // centers no longer needed
    __syncthreads();
    if (w >= 4) {
        float* p = &scratch[((w - 4) * 64 + t) * SST];
#pragma unroll
        for (int r = 0; r < RPL; ++r)
#pragma unroll
            for (int c = 0; c < NCLS; ++c) p[r * NCLS + c] = acc[r][c];
    }
    __syncthreads();
    if (w < 4) {
        const float* p = &scratch[(w * 64 + t) * SST];
#pragma unroll
        for (int r = 0; r < RPL; ++r)
#pragma unroll
            for (int c = 0; c < NCLS; ++c) acc[r][c] += p[r * NCLS + c];
    }
    __syncthreads();
    if (w == 2 || w == 3) {
        float* p = &scratch[((w - 2) * 64 + t) * SST];
#pragma unroll
        for (int r = 0; r < RPL; ++r)
#pragma unroll
            for (int c = 0; c < NCLS; ++c) p[r * NCLS + c] = acc[r][c];
    }
    __syncthreads();
    if (w < 2) {
        const float* p = &scratch[(w * 64 + t) * SST];
#pragma unroll
        for (int r = 0; r < RPL; ++r)
#pragma unroll
            for (int c = 0; c < NCLS; ++c) acc[r][c] += p[r * NCLS + c];
    }
    __syncthreads();
    if (w == 1) {
        float* p = &scratch[t * SST];
#pragma unroll
        for (int r = 0; r < RPL; ++r)
#pragma unroll
            for (int c = 0; c < NCLS; ++c) p[r * NCLS + c] = acc[r][c];
    }
    __syncthreads();
    if (w == 0) {
        const float* p = &scratch[t * SST];
        float vsum = 0.f;
#pragma unroll
        for (int r = 0; r < RPL; ++r) {
            const int lab = labv[r];
            float pos = 0.f, neg = FLT_MAX;
#pragma unroll
            for (int c = 0; c < NCLS; ++c) {
                float e = halfc2[c] - (acc[r][c] + p[r * NCLS + c]);
                pos = (c == lab) ? e : pos;
                neg = (c == lab) ? neg : fminf(neg, e);
            }
            vsum += fmaxf(pos + MARGIN_V - neg, 0.f);
        }
#pragma unroll
        for (int off = 32; off > 0; off >>= 1)
            vsum += __shfl_down(vsum, off, 64);
        if (t == 0) atomicAdd(out, vsum * (1.0f / 65536.f));
    }
}

extern "C" void kernel_launch(void* const* d_in, const int* in_sizes, int n_in,
                              void* d_out, int out_size, void* d_ws, size_t ws_size,
                              hipStream_t stream) {
    const float* feat    = (const float*)d_in[0];   // (65536, 512) fp32
    const float* centers = (const float*)d_in[1];   // (21, 512) fp32
    const int*   labels  = (const int*)d_in[2];     // (65536,) int
    float* out    = (float*)d_out;                  // scalar loss
    float* halfc2 = (float*)d_ws;                   // 21 floats scratch

    hipMemsetAsync(d_out, 0, (size_t)out_size * sizeof(float), stream);
    center_norm_kernel<<<NCLS, 64, 0, stream>>>(centers, halfc2);

    const int nblocks = 65536 / ROWS_PB;            // 256 blocks x 8 waves = 1 block/CU
    tcl_main_kernel<<<nblocks, 512, 0, stream>>>(feat, centers, labels, halfc2, out);
}

// Round 8
// 217.052 us; speedup vs baseline: 1.6425x; 1.6425x over previous
//
#include <hip/hip_runtime.h>
#include <float.h>

#define DIM      512
#define NCLS     21
#define MARGIN_V 5.0f
#define NWAVES   4                  // waves per block (256 threads -> 256-VGPR cap)
#define DSLICE   (DIM / NWAVES)     // 128 floats per wave's d-slice
#define RPL      4                  // rows per lane: center b128 feeds 16 FMAs
#define ROWS_PB  (64 * RPL)         // 256 rows per block; grid 256 = 1 block/CU
#define CHFLT    8                  // floats per chunk (2 float4, back-to-back)
#define NCHUNK   (DSLICE / CHFLT)   // 16
#define CLDSF    (NCLS * DIM)       // 10752 floats: centers table (43008 B)
#define SST      (RPL * NCLS + 1)   // 85: odd combine stride -> conflict-free b32
#define LDSF     (2 * 64 * SST)     // 10880 floats = 43520 B (>= centers 43008)

// Kernel 1: halfc2[c] = 0.5 * ||centers[c]||^2  -> d_ws
__global__ __launch_bounds__(64)
void center_norm_kernel(const float* __restrict__ centers,
                        float* __restrict__ halfc2) {
    const int c = blockIdx.x;
    const int t = threadIdx.x;
    float s = 0.f;
#pragma unroll
    for (int i = 0; i < DIM / 64; ++i) {
        float v = centers[c * DIM + i * 64 + t];
        s = fmaf(v, v, s);
    }
#pragma unroll
    for (int off = 32; off > 0; off >>= 1)
        s += __shfl_down(s, off, 64);
    if (t == 0) halfc2[c] = 0.5f * s;
}

// Kernel 2: 256 threads = 4 waves (so the compiler's 8-waves/CU heuristic
// grants a 256-VGPR cap -- every 512-thread variant (r3/r5/r7) was clamped to
// 128 and spilled). Wave w owns d-slice [w*128, w*128+128) of 256 rows; lane t
// owns rows {t,t+64,t+128,t+192}: acc[4][21]=84 VGPRs. Features global->VGPR
// in 8-float chunks with explicit fA/fB ping-pong (32+32 regs in flight);
// a 64B line's two halves are one compute phase apart -> L2 window ~1MB/XCD
// << 4MB, HBM fetch exact. Centers broadcast from LDS: one uniform
// ds_read_b128 per 16 FMAs -> DS pipe 13.4us/CU, under the 21us HBM floor.
__global__ __launch_bounds__(256)
void tcl_main_kernel(const float* __restrict__ feat,
                     const float* __restrict__ centers,
                     const int* __restrict__ labels,
                     const float* __restrict__ halfc2,
                     float* __restrict__ out) {
    __shared__ float lds_f[LDSF];

    const int tid  = threadIdx.x;
    const int w    = __builtin_amdgcn_readfirstlane(tid >> 6);  // uniform wave id
    const int t    = tid & 63;
    const int row0 = blockIdx.x * ROWS_PB;

    int labv[RPL];
    if (w == 0) {
#pragma unroll
        for (int r = 0; r < RPL; ++r) labv[r] = labels[row0 + t + r * 64];
    }

    float acc[RPL][NCLS];
#pragma unroll
    for (int r = 0; r < RPL; ++r)
#pragma unroll
        for (int c = 0; c < NCLS; ++c) acc[r][c] = 0.f;

    const float4* f4p = reinterpret_cast<const float4*>(feat);
    size_t rb[RPL];
#pragma unroll
    for (int r = 0; r < RPL; ++r)
        rb[r] = (size_t)(row0 + t + r * 64) * (DIM / 4) + (size_t)w * (DSLICE / 4);

    // stage centers table into LDS (block-cooperative, float4)
    float4* l4 = reinterpret_cast<float4*>(lds_f);
    {
        const float4* c4 = reinterpret_cast<const float4*>(centers);
#pragma unroll
        for (int i = 0; i < (CLDSF / 4 + 255) / 256; ++i) {
            int idx = i * 256 + tid;
            if (idx < CLDSF / 4) l4[idx] = c4[idx];
        }
    }
    __syncthreads();

    // uniform LDS base of this wave's d-slice; class offsets are immediates
    const float4* cl = l4 + w * (DSLICE / 4);

    auto LOADC = [&](float4 (&dst)[RPL][2], int kk) {
#pragma unroll
        for (int r = 0; r < RPL; ++r)
#pragma unroll
            for (int j = 0; j < 2; ++j)
                dst[r][j] = f4p[rb[r] + kk * 2 + j];
    };
    auto COMPUTE = [&](const float4 (&f)[RPL][2], int kk) {
#pragma unroll
        for (int q = 0; q < 2; ++q) {
            const int fq = kk * 2 + q;      // f4 index within slice, 0..31
            // 3 groups of 7 classes bound center liveness to 28 VGPRs
#pragma unroll
            for (int ch = 0; ch < 3; ++ch) {
                float4 cv[7];
#pragma unroll
                for (int k7 = 0; k7 < 7; ++k7)
                    cv[k7] = cl[(ch * 7 + k7) * (DIM / 4) + fq];
#pragma unroll
                for (int k7 = 0; k7 < 7; ++k7) {
                    const int c = ch * 7 + k7;
#pragma unroll
                    for (int r = 0; r < RPL; ++r) {
                        acc[r][c] = fmaf(f[r][q].x, cv[k7].x,
                                     fmaf(f[r][q].y, cv[k7].y,
                                      fmaf(f[r][q].z, cv[k7].z,
                                       fmaf(f[r][q].w, cv[k7].w, acc[r][c]))));
                    }
                }
            }
        }
    };

    // software pipeline: ping-pong fA/fB, loads one compute phase ahead
    float4 fA[RPL][2], fB[RPL][2];
    LOADC(fA, 0);
#pragma unroll 1
    for (int k = 0; k < NCHUNK - 2; k += 2) {
        LOADC(fB, k + 1);
        COMPUTE(fA, k);
        LOADC(fA, k + 2);
        COMPUTE(fB, k + 1);
    }
    LOADC(fB, NCHUNK - 1);
    COMPUTE(fA, NCHUNK - 2);
    COMPUTE(fB, NCHUNK - 1);

    // ---- cross-wave combine: 4 -> 2 -> 1, scalar b32, odd stride 85 ----
    float* scratch = lds_f;   // centers no longer needed
    __syncthreads();
    if (w >= 2) {
        float* p = &scratch[((w - 2) * 64 + t) * SST];
#pragma unroll
        for (int r = 0; r < RPL; ++r)
#pragma unroll
            for (int c = 0; c < NCLS; ++c) p[r * NCLS + c] = acc[r][c];
    }
    __syncthreads();
    if (w < 2) {
        const float* p = &scratch[(w * 64 + t) * SST];
#pragma unroll
        for (int r = 0; r < RPL; ++r)
#pragma unroll
            for (int c = 0; c < NCLS; ++c) acc[r][c] += p[r * NCLS + c];
    }
    __syncthreads();
    if (w == 1) {
        float* p = &scratch[t * SST];
#pragma unroll
        for (int r = 0; r < RPL; ++r)
#pragma unroll
            for (int c = 0; c < NCLS; ++c) p[r * NCLS + c] = acc[r][c];
    }
    __syncthreads();
    if (w == 0) {
        const float* p = &scratch[t * SST];
        float vsum = 0.f;
#pragma unroll
        for (int r = 0; r < RPL; ++r) {
            const int lab = labv[r];
            float pos = 0.f, neg = FLT_MAX;
#pragma unroll
            for (int c = 0; c < NCLS; ++c) {
                float e = halfc2[c] - (acc[r][c] + p[r * NCLS + c]);
                pos = (c == lab) ? e : pos;
                neg = (c == lab) ? neg : fminf(neg, e);
            }
            vsum += fmaxf(pos + MARGIN_V - neg, 0.f);
        }
#pragma unroll
        for (int off = 32; off > 0; off >>= 1)
            vsum += __shfl_down(vsum, off, 64);
        if (t == 0) atomicAdd(out, vsum * (1.0f / 65536.f));
    }
}

extern "C" void kernel_launch(void* const* d_in, const int* in_sizes, int n_in,
                              void* d_out, int out_size, void* d_ws, size_t ws_size,
                              hipStream_t stream) {
    const float* feat    = (const float*)d_in[0];   // (65536, 512) fp32
    const float* centers = (const float*)d_in[1];   // (21, 512) fp32
    const int*   labels  = (const int*)d_in[2];     // (65536,) int
    float* out    = (float*)d_out;                  // scalar loss
    float* halfc2 = (float*)d_ws;                   // 21 floats scratch

    hipMemsetAsync(d_out, 0, (size_t)out_size * sizeof(float), stream);
    center_norm_kernel<<<NCLS, 64, 0, stream>>>(centers, halfc2);

    const int nblocks = 65536 / ROWS_PB;            // 256 blocks x 4 waves = 1 block/CU
    tcl_main_kernel<<<nblocks, 256, 0, stream>>>(feat, centers, labels, halfc2, out);
}

// Round 9
// 213.517 us; speedup vs baseline: 1.6697x; 1.0166x over previous
//
#include <hip/hip_runtime.h>
#include <float.h>

#define DIM      512
#define NCLS     21
#define MARGIN_V 5.0f
#define NWAVES   4                  // waves per block (256 threads; VGPR cap 256)
#define DSLICE   (DIM / NWAVES)     // 128 floats per wave's d-slice
#define RPL      2                  // rows per lane -> acc[2][21]=42; grid doubles to 512
#define ROWS_PB  (64 * RPL)         // 128 rows per block; grid 512 = 2 blocks/CU
#define CHFLT    16                 // full 64B line per row per chunk (4 dwordx4)
#define NCHUNK   (DSLICE / CHFLT)   // 8
#define CLDSF    (NCLS * DIM)       // 10752 floats: centers table (43008 B)
#define SST      (RPL * NCLS + 1)   // 43: odd combine stride -> conflict-free b32
#define LDSF     CLDSF              // combine scratch (2*64*43=5504) fits inside

// Kernel 1: halfc2[c] = 0.5 * ||centers[c]||^2  -> d_ws
__global__ __launch_bounds__(64)
void center_norm_kernel(const float* __restrict__ centers,
                        float* __restrict__ halfc2) {
    const int c = blockIdx.x;
    const int t = threadIdx.x;
    float s = 0.f;
#pragma unroll
    for (int i = 0; i < DIM / 64; ++i) {
        float v = centers[c * DIM + i * 64 + t];
        s = fmaf(v, v, s);
    }
#pragma unroll
    for (int off = 32; off > 0; off >>= 1)
        s += __shfl_down(s, off, 64);
    if (t == 0) halfc2[c] = 0.5f * s;
}

// Kernel 2: 256-thread / 4-wave blocks (VGPR cap 256, r8-verified); wave w owns
// d-slice [w*128, w*128+128) of 128 rows; lane t owns rows {t, t+64}.
// r8 post-mortem: 1 wave/SIMD + unpinned loads = every DS/VMEM latency paid
// serially (~79us modeled ~= 77.6 measured). Fixes here: (1) RPL=2 halves
// rows/block -> grid 512 -> 2 blocks/CU -> 2 waves/SIMD of TLP; (2) full-line
// 16-float chunks: each row's 64B line consumed by 4 back-to-back dwordx4
// (fetch-exact with no cache-window assumption); (3) fA/fB ping-pong re-pinned
// with sched_barrier(0) -- load-to-use distance = one chunk compute (~2.3K cyc
// >> 900cy HBM). Centers broadcast from LDS (uniform b128, 1 read / 8 FMAs):
// DS pipe ~27us/CU is the predicted ceiling; HBM 21us; VALU 9us.
__global__ __launch_bounds__(256)
void tcl_main_kernel(const float* __restrict__ feat,
                     const float* __restrict__ centers,
                     const int* __restrict__ labels,
                     const float* __restrict__ halfc2,
                     float* __restrict__ out) {
    __shared__ float lds_f[LDSF];

    const int tid  = threadIdx.x;
    const int w    = __builtin_amdgcn_readfirstlane(tid >> 6);  // uniform wave id
    const int t    = tid & 63;
    const int row0 = blockIdx.x * ROWS_PB;

    int labv[RPL];
    if (w == 0) {
#pragma unroll
        for (int r = 0; r < RPL; ++r) labv[r] = labels[row0 + t + r * 64];
    }

    float acc[RPL][NCLS];
#pragma unroll
    for (int r = 0; r < RPL; ++r)
#pragma unroll
        for (int c = 0; c < NCLS; ++c) acc[r][c] = 0.f;

    const float4* f4p = reinterpret_cast<const float4*>(feat);
    size_t rb[RPL];
#pragma unroll
    for (int r = 0; r < RPL; ++r)
        rb[r] = (size_t)(row0 + t + r * 64) * (DIM / 4) + (size_t)w * (DSLICE / 4);

    auto LOADC = [&](float4 (&dst)[RPL][4], int kk) {
#pragma unroll
        for (int r = 0; r < RPL; ++r)
#pragma unroll
            for (int j = 0; j < 4; ++j)          // 4 back-to-back dwordx4 = full 64B line
                dst[r][j] = f4p[rb[r] + kk * 4 + j];
    };

    // issue chunk-0 loads first; they fly under center staging
    float4 fA[RPL][4], fB[RPL][4];
    LOADC(fA, 0);
    __builtin_amdgcn_sched_barrier(0);

    // stage centers table into LDS (block-cooperative, float4)
    float4* l4 = reinterpret_cast<float4*>(lds_f);
    {
        const float4* c4 = reinterpret_cast<const float4*>(centers);
#pragma unroll
        for (int i = 0; i < (CLDSF / 4 + 255) / 256; ++i) {
            int idx = i * 256 + tid;
            if (idx < CLDSF / 4) l4[idx] = c4[idx];
        }
    }
    __syncthreads();

    const float4* cl = l4 + w * (DSLICE / 4);   // uniform base of this wave's d-slice

    auto COMPUTE = [&](const float4 (&f)[RPL][4], int kk) {
#pragma unroll
        for (int q = 0; q < 4; ++q) {
            const int fq = kk * 4 + q;          // f4 index within slice, 0..31
            // 3 groups of 7 classes bound center liveness to 28 VGPRs
#pragma unroll
            for (int ch = 0; ch < 3; ++ch) {
                float4 cv[7];
#pragma unroll
                for (int k7 = 0; k7 < 7; ++k7)
                    cv[k7] = cl[(ch * 7 + k7) * (DIM / 4) + fq];
#pragma unroll
                for (int k7 = 0; k7 < 7; ++k7) {
                    const int c = ch * 7 + k7;
#pragma unroll
                    for (int r = 0; r < RPL; ++r) {
                        acc[r][c] = fmaf(f[r][q].x, cv[k7].x,
                                     fmaf(f[r][q].y, cv[k7].y,
                                      fmaf(f[r][q].z, cv[k7].z,
                                       fmaf(f[r][q].w, cv[k7].w, acc[r][c]))));
                    }
                }
            }
        }
    };

    // pinned software pipeline: loads one full chunk-compute ahead
#pragma unroll 1
    for (int k = 0; k < NCHUNK - 2; k += 2) {
        LOADC(fB, k + 1);
        __builtin_amdgcn_sched_barrier(0);
        COMPUTE(fA, k);
        __builtin_amdgcn_sched_barrier(0);
        LOADC(fA, k + 2);
        __builtin_amdgcn_sched_barrier(0);
        COMPUTE(fB, k + 1);
        __builtin_amdgcn_sched_barrier(0);
    }
    LOADC(fB, NCHUNK - 1);
    __builtin_amdgcn_sched_barrier(0);
    COMPUTE(fA, NCHUNK - 2);
    COMPUTE(fB, NCHUNK - 1);

    // ---- cross-wave combine: 4 -> 2 -> 1, scalar b32, odd stride 43 ----
    float* scratch = lds_f;   // centers no longer needed
    __syncthreads();
    if (w >= 2) {
        float* p = &scratch[((w - 2) * 64 + t) * SST];
#pragma unroll
        for (int r = 0; r < RPL; ++r)
#pragma unroll
            for (int c = 0; c < NCLS; ++c) p[r * NCLS + c] = acc[r][c];
    }
    __syncthreads();
    if (w < 2) {
        const float* p = &scratch[(w * 64 + t) * SST];
#pragma unroll
        for (int r = 0; r < RPL; ++r)
#pragma unroll
            for (int c = 0; c < NCLS; ++c) acc[r][c] += p[r * NCLS + c];
    }
    __syncthreads();
    if (w == 1) {
        float* p = &scratch[t * SST];
#pragma unroll
        for (int r = 0; r < RPL; ++r)
#pragma unroll
            for (int c = 0; c < NCLS; ++c) p[r * NCLS + c] = acc[r][c];
    }
    __syncthreads();
    if (w == 0) {
        const float* p = &scratch[t * SST];
        float vsum = 0.f;
#pragma unroll
        for (int r = 0; r < RPL; ++r) {
            const int lab = labv[r];
            float pos = 0.f, neg = FLT_MAX;
#pragma unroll
            for (int c = 0; c < NCLS; ++c) {
                float e = halfc2[c] - (acc[r][c] + p[r * NCLS + c]);
                pos = (c == lab) ? e : pos;
                neg = (c == lab) ? neg : fminf(neg, e);
            }
            vsum += fmaxf(pos + MARGIN_V - neg, 0.f);
        }
#pragma unroll
        for (int off = 32; off > 0; off >>= 1)
            vsum += __shfl_down(vsum, off, 64);
        if (t == 0) atomicAdd(out, vsum * (1.0f / 65536.f));
    }
}

extern "C" void kernel_launch(void* const* d_in, const int* in_sizes, int n_in,
                              void* d_out, int out_size, void* d_ws, size_t ws_size,
                              hipStream_t stream) {
    const float* feat    = (const float*)d_in[0];   // (65536, 512) fp32
    const float* centers = (const float*)d_in[1];   // (21, 512) fp32
    const int*   labels  = (const int*)d_in[2];     // (65536,) int
    float* out    = (float*)d_out;                  // scalar loss
    float* halfc2 = (float*)d_ws;                   // 21 floats scratch

    hipMemsetAsync(d_out, 0, (size_t)out_size * sizeof(float), stream);
    center_norm_kernel<<<NCLS, 64, 0, stream>>>(centers, halfc2);

    const int nblocks = 65536 / ROWS_PB;            // 512 blocks x 4 waves = 2 blocks/CU
    tcl_main_kernel<<<nblocks, 256, 0, stream>>>(feat, centers, labels, halfc2, out);
}

// Round 10
// 211.062 us; speedup vs baseline: 1.6891x; 1.0116x over previous
//
#include <hip/hip_runtime.h>
#include <float.h>

#define DIM      512
#define NCLS     21
#define MARGIN_V 5.0f
#define NWAVES   4                  // waves per block (256 threads; VGPR cap 256)
#define DSLICE   (DIM / NWAVES)     // 128 floats per wave's d-slice
#define RPL      2                  // rows per lane -> grid 512 = 2 blocks/CU
#define ROWS_PB  (64 * RPL)         // 128 rows per block
#define CHFLT    8                  // floats per chunk per row (2 float4)
#define NCHUNK   (DSLICE / CHFLT)   // 16
#define NF4      (DIM / 4)          // 128 f4 per row
#define CT_F4    (NF4 * NCLS)       // 2688 float4 = 43008 B transposed centers
#define SST      (RPL * NCLS + 1)   // 43: odd combine stride -> conflict-free b32
#define LDSF     (CT_F4 * 4)        // 10752 floats (combine scratch 5504 fits inside)

// Kernel 1: halfc2[c] = 0.5 * ||centers[c]||^2  -> d_ws
__global__ __launch_bounds__(64)
void center_norm_kernel(const float* __restrict__ centers,
                        float* __restrict__ halfc2) {
    const int c = blockIdx.x;
    const int t = threadIdx.x;
    float s = 0.f;
#pragma unroll
    for (int i = 0; i < DIM / 64; ++i) {
        float v = centers[c * DIM + i * 64 + t];
        s = fmaf(v, v, s);
    }
#pragma unroll
    for (int off = 32; off > 0; off >>= 1)
        s += __shfl_down(s, off, 64);
    if (t == 0) halfc2[c] = 0.5f * s;
}

// Kernel 2. r2/r8/r9 all pinned at ~71-78us across 1/2/8 waves-per-SIMD: the
// invariant is per-ds_read latency exposure on the center broadcasts (672
// reads x ~240cy serial ~= the measured 185Kcyc/SIMD). Fix: TRANSPOSED center
// layout in LDS -- ctr[g][c] f4-major, so one q-step's 21 class-values are 21
// CONSECUTIVE 16B words, loaded as one contiguous ds_read_b128 burst into
// cv[21] (one ~300cy latency window for all 21, incremental lgkmcnt overlap
// with the 168 FMAs). Per wave: 32 q-steps x ~300cy + 10.7Kcy FMA ~= 25Kcyc;
// 2 waves/SIMD -> bound becomes DS issue throughput ~27us/CU.
// 256-thr/4-wave blocks (VGPR cap 256, r8-verified); RPL=2; fA/fB ping-pong;
// liveness ~= 42 acc + 84 cv + 32 fbuf + addr ~= 178 regs, no spills.
__global__ __launch_bounds__(256)
void tcl_main_kernel(const float* __restrict__ feat,
                     const float* __restrict__ centers,
                     const int* __restrict__ labels,
                     const float* __restrict__ halfc2,
                     float* __restrict__ out) {
    __shared__ float lds_f[LDSF];

    const int tid  = threadIdx.x;
    const int w    = __builtin_amdgcn_readfirstlane(tid >> 6);  // uniform wave id
    const int t    = tid & 63;
    const int row0 = blockIdx.x * ROWS_PB;

    int labv[RPL];
    if (w == 0) {
#pragma unroll
        for (int r = 0; r < RPL; ++r) labv[r] = labels[row0 + t + r * 64];
    }

    float acc[RPL][NCLS];
#pragma unroll
    for (int r = 0; r < RPL; ++r)
#pragma unroll
        for (int c = 0; c < NCLS; ++c) acc[r][c] = 0.f;

    const float4* f4p = reinterpret_cast<const float4*>(feat);
    const int g0 = w * (DSLICE / 4);            // wave's base f4-index, 0..127
    size_t rb[RPL];
#pragma unroll
    for (int r = 0; r < RPL; ++r)
        rb[r] = (size_t)(row0 + t + r * 64) * NF4 + g0;

    auto LOADC = [&](float4 (&dst)[RPL][2], int kk) {
#pragma unroll
        for (int r = 0; r < RPL; ++r)
#pragma unroll
            for (int j = 0; j < 2; ++j)
                dst[r][j] = f4p[rb[r] + kk * 2 + j];
    };

    // issue chunk-0 feature loads first; they fly under center staging
    float4 fA[RPL][2], fB[RPL][2];
    LOADC(fA, 0);
    __builtin_amdgcn_sched_barrier(0);

    // stage centers TRANSPOSED into LDS: ctr[g*21 + c] = centers_f4[c*128 + g].
    // Global side coalesced (idx consecutive); LDS write side strided (8-way
    // conflict, ~11 instrs/thread -- negligible one-time cost).
    float4* ct = reinterpret_cast<float4*>(lds_f);
    {
        const float4* c4 = reinterpret_cast<const float4*>(centers);
#pragma unroll
        for (int i = 0; i < (CT_F4 + 255) / 256; ++i) {
            int idx = i * 256 + tid;
            if (idx < CT_F4) {
                float4 v = c4[idx];
                int c = idx >> 7;           // idx / 128
                int g = idx & (NF4 - 1);    // idx % 128
                ct[g * NCLS + c] = v;
            }
        }
    }
    __syncthreads();

    auto COMPUTE = [&](const float4 (&f)[RPL][2], int kk) {
#pragma unroll
        for (int q = 0; q < 2; ++q) {
            const int gq = g0 + kk * 2 + q;     // global f4-index of this q-step
            const float4* cbase = &ct[gq * NCLS];
            // one contiguous burst of 21 uniform b128 reads (imm offsets 0..320B)
            float4 cv[NCLS];
#pragma unroll
            for (int c = 0; c < NCLS; ++c) cv[c] = cbase[c];
#pragma unroll
            for (int c = 0; c < NCLS; ++c) {
#pragma unroll
                for (int r = 0; r < RPL; ++r) {
                    acc[r][c] = fmaf(f[r][q].x, cv[c].x,
                                 fmaf(f[r][q].y, cv[c].y,
                                  fmaf(f[r][q].z, cv[c].z,
                                   fmaf(f[r][q].w, cv[c].w, acc[r][c]))));
                }
            }
        }
    };

    // ping-pong pipeline: loads one chunk-compute ahead of use
#pragma unroll 1
    for (int k = 0; k < NCHUNK - 2; k += 2) {
        LOADC(fB, k + 1);
        __builtin_amdgcn_sched_barrier(0);
        COMPUTE(fA, k);
        LOADC(fA, k + 2);
        __builtin_amdgcn_sched_barrier(0);
        COMPUTE(fB, k + 1);
    }
    LOADC(fB, NCHUNK - 1);
    __builtin_amdgcn_sched_barrier(0);
    COMPUTE(fA, NCHUNK - 2);
    COMPUTE(fB, NCHUNK - 1);

    // ---- cross-wave combine: 4 -> 2 -> 1, scalar b32, odd stride 43 ----
    float* scratch = lds_f;   // centers no longer needed
    __syncthreads();
    if (w >= 2) {
        float* p = &scratch[((w - 2) * 64 + t) * SST];
#pragma unroll
        for (int r = 0; r < RPL; ++r)
#pragma unroll
            for (int c = 0; c < NCLS; ++c) p[r * NCLS + c] = acc[r][c];
    }
    __syncthreads();
    if (w < 2) {
        const float* p = &scratch[(w * 64 + t) * SST];
#pragma unroll
        for (int r = 0; r < RPL; ++r)
#pragma unroll
            for (int c = 0; c < NCLS; ++c) acc[r][c] += p[r * NCLS + c];
    }
    __syncthreads();
    if (w == 1) {
        float* p = &scratch[t * SST];
#pragma unroll
        for (int r = 0; r < RPL; ++r)
#pragma unroll
            for (int c = 0; c < NCLS; ++c) p[r * NCLS + c] = acc[r][c];
    }
    __syncthreads();
    if (w == 0) {
        const float* p = &scratch[t * SST];
        float vsum = 0.f;
#pragma unroll
        for (int r = 0; r < RPL; ++r) {
            const int lab = labv[r];
            float pos = 0.f, neg = FLT_MAX;
#pragma unroll
            for (int c = 0; c < NCLS; ++c) {
                float e = halfc2[c] - (acc[r][c] + p[r * NCLS + c]);
                pos = (c == lab) ? e : pos;
                neg = (c == lab) ? neg : fminf(neg, e);
            }
            vsum += fmaxf(pos + MARGIN_V - neg, 0.f);
        }
#pragma unroll
        for (int off = 32; off > 0; off >>= 1)
            vsum += __shfl_down(vsum, off, 64);
        if (t == 0) atomicAdd(out, vsum * (1.0f / 65536.f));
    }
}

extern "C" void kernel_launch(void* const* d_in, const int* in_sizes, int n_in,
                              void* d_out, int out_size, void* d_ws, size_t ws_size,
                              hipStream_t stream) {
    const float* feat    = (const float*)d_in[0];   // (65536, 512) fp32
    const float* centers = (const float*)d_in[1];   // (21, 512) fp32
    const int*   labels  = (const int*)d_in[2];     // (65536,) int
    float* out    = (float*)d_out;                  // scalar loss
    float* halfc2 = (float*)d_ws;                   // 21 floats scratch

    hipMemsetAsync(d_out, 0, (size_t)out_size * sizeof(float), stream);
    center_norm_kernel<<<NCLS, 64, 0, stream>>>(centers, halfc2);

    const int nblocks = 65536 / ROWS_PB;            // 512 blocks x 4 waves = 2 blocks/CU
    tcl_main_kernel<<<nblocks, 256, 0, stream>>>(feat, centers, labels, halfc2, out);
}